// Round 5
// baseline (370.113 us; speedup 1.0000x reference)
//
#include <hip/hip_runtime.h>
#include <math.h>

#define B5 5
#define DX 4096
#define DT 4096
#define DR 4097   // T + D

// ---------------- workspace layout (floats) ----------------
enum {
  WS_H1   = 0,                     // accumulators (zeroed every call by k_zero)
  WS_QXI  = WS_H1  + 20480,
  WS_LQC  = WS_QXI + 20480,
  WS_ZM   = WS_LQC + 20480,
  WS_ZC   = WS_ZM  + 20480,
  WS_H23  = WS_ZC  + 20480,
  WS_RM   = WS_H23 + 20480,        // 5*4097
  WS_RC   = WS_RM  + 20485,
  WS_H3   = WS_RC  + 20485,
  WS_XM   = WS_H3  + 20480,
  WS_XC   = WS_XM  + 20480,
  WS_SUMS = WS_XC  + 20480,        // [kld1, kld2, nll]
  WS_CNT1 = WS_SUMS + 3,           // ard completion counter (int)
  WS_CNT2,                         // fin completion counter (int)
  WS_ACCUM_END,
  // not zeroed (always written before read each call):
  WS_Z    = WS_ACCUM_END,          // 20480
  WS_KSS  = WS_Z + 20480,          // 25
  WS_KXS  = WS_KSS + 25,           // 25
  WS_F    = WS_KXS + 25,           // 5
  WS_QFM  = WS_F + 5,              // 5
  WS_QFC  = WS_QFM + 5,            // 5
  WS_END
};

#define KSPAN  32
#define GBLOCK 256

__device__ inline float wave_sum(float v) {
  #pragma unroll
  for (int o = 32; o > 0; o >>= 1) v += __shfl_down(v, o, 64);
  return v;
}

// ---------------- zero the accumulator region ----------------
__global__ __launch_bounds__(256) void k_zero(float* __restrict__ ws, int n)
{
  int i = (blockIdx.x * 256 + threadIdx.x) * 4;
  if (i + 3 < n) {
    *(float4*)(ws + i) = make_float4(0.f, 0.f, 0.f, 0.f);
  } else {
    for (int c = 0; c < 4; ++c) if (i + c < n) ws[i + c] = 0.f;
  }
}

// ---------------- GEMM body: Y[5,dout] += prolog(.)[5,din] @ W ----------------
// 2 cols/thread, float2 weight loads, KSPAN=32 k-rows/block (split-K atomics).
// PROLOG: 0 raw p0 ; 1 relu(p0 + p1[k]) ; 2 relu(p0[b]*p1[k] + p2[k]) ;
//         3 concat: k<4096 -> p0 (x), else p1 (z)
template<int PROLOG, int DUAL, int ALIGNED>
__device__ __forceinline__ void gemm5_body(
    float sx[B5][KSPAN], int bx, int by,
    const float* __restrict__ p0, const float* __restrict__ p1,
    const float* __restrict__ p2,
    const float* __restrict__ Wa, const float* __restrict__ Wb,
    float* __restrict__ Ya,       float* __restrict__ Yb,
    int din, int dout)
{
  const int tid = threadIdx.x;
  const long i0 = (long)by * KSPAN;

  if (tid < B5 * KSPAN) {           // 160 threads stage activations
    int b  = tid >> 5;              // KSPAN == 32
    int il = tid & 31;
    int i  = (int)i0 + il;
    float v;
    if (PROLOG == 0)      v = p0[(long)b * din + i];
    else if (PROLOG == 1) v = fmaxf(p0[(long)b * din + i] + p1[i], 0.f);
    else if (PROLOG == 2) v = fmaxf(p0[b] * p1[i] + p2[i], 0.f);
    else                  v = (i < DX) ? p0[(long)b * DX + i] : p1[(long)b * DT + (i - DX)];
    sx[b][il] = v;
  }
  __syncthreads();

  long o0 = ((long)bx * GBLOCK + tid) * 2;
  if (o0 >= dout) return;
  const bool has2 = (o0 + 1 < dout);

  float accA[B5][2] = {};
  float accB[B5][2] = {};

  const float* wa = Wa + i0 * dout + o0;
  const float* wb = DUAL ? (Wb + i0 * dout + o0) : nullptr;

  #pragma unroll 2
  for (int k4 = 0; k4 < KSPAN; k4 += 4) {
    float4 xv[B5];
    #pragma unroll
    for (int b = 0; b < B5; ++b) xv[b] = *(const float4*)&sx[b][k4];

    float2 la[4], lb[4];
    #pragma unroll
    for (int u = 0; u < 4; ++u) {
      const float* pa = wa + (long)u * dout;
      if (ALIGNED) la[u] = *(const float2*)pa;
      else { la[u].x = pa[0]; la[u].y = has2 ? pa[1] : 0.f; }
      if (DUAL) {
        const float* pb = wb + (long)u * dout;
        if (ALIGNED) lb[u] = *(const float2*)pb;
        else { lb[u].x = pb[0]; lb[u].y = has2 ? pb[1] : 0.f; }
      }
    }
    #pragma unroll
    for (int u = 0; u < 4; ++u) {
      #pragma unroll
      for (int b = 0; b < B5; ++b) {
        float xb = (u == 0) ? xv[b].x : (u == 1) ? xv[b].y : (u == 2) ? xv[b].z : xv[b].w;
        accA[b][0] += xb * la[u].x; accA[b][1] += xb * la[u].y;
        if (DUAL) { accB[b][0] += xb * lb[u].x; accB[b][1] += xb * lb[u].y; }
      }
    }
    wa += 4 * (long)dout; if (DUAL) wb += 4 * (long)dout;
  }

  #pragma unroll
  for (int b = 0; b < B5; ++b) {
    atomicAdd(&Ya[(long)b * dout + o0], accA[b][0]);
    if (has2) atomicAdd(&Ya[(long)b * dout + o0 + 1], accA[b][1]);
    if (DUAL) {
      atomicAdd(&Yb[(long)b * dout + o0], accB[b][0]);
      if (has2) atomicAdd(&Yb[(long)b * dout + o0 + 1], accB[b][1]);
    }
  }
}

// single-GEMM wrapper
template<int PROLOG, int DUAL, int ALIGNED>
__global__ __launch_bounds__(GBLOCK) void gemm5(
    const float* __restrict__ p0, const float* __restrict__ p1,
    const float* __restrict__ p2,
    const float* __restrict__ Wa, const float* __restrict__ Wb,
    float* __restrict__ Ya,       float* __restrict__ Yb,
    int din, int dout)
{
  __shared__ float sx[B5][KSPAN];
  gemm5_body<PROLOG, DUAL, ALIGNED>(sx, blockIdx.x, blockIdx.y,
      p0, p1, p2, Wa, Wb, Ya, Yb, din, dout);
}

// merged G4 (concat(x,z)@W23) + G6 (z@W3): independent, one launch
#define G4_BLOCKS (8 * 256)   // x=8 chunks, y=8192/32
__global__ __launch_bounds__(GBLOCK) void gemm5_G46(
    const float* __restrict__ x,   const float* __restrict__ z,
    const float* __restrict__ W23, float* __restrict__ H23,
    const float* __restrict__ W3,  float* __restrict__ H3)
{
  __shared__ float sx[B5][KSPAN];
  int id = blockIdx.x;
  if (id < G4_BLOCKS) {
    gemm5_body<3, 0, 1>(sx, id & 7, id >> 3, x, z, nullptr,
                        W23, nullptr, H23, nullptr, 8192, 4096);
  } else {
    id -= G4_BLOCKS;
    gemm5_body<0, 0, 1>(sx, id & 7, id >> 3, z, nullptr, nullptr,
                        W3, nullptr, H3, nullptr, 4096, 4096);
  }
}

// merged G5 (relu(h23+b23)@[W24,W25], dout=4097) + G7 (relu(h3+b3)@[W31,W32])
#define G5_BLOCKS (9 * 128)   // x=9 chunks (4097 cols), y=4096/32
__global__ __launch_bounds__(GBLOCK) void gemm5_G57(
    const float* __restrict__ H23, const float* __restrict__ b23,
    const float* __restrict__ W24, const float* __restrict__ W25,
    float* __restrict__ RM,        float* __restrict__ RC,
    const float* __restrict__ H3,  const float* __restrict__ b3,
    const float* __restrict__ W31, const float* __restrict__ W32,
    float* __restrict__ XM,        float* __restrict__ XC)
{
  __shared__ float sx[B5][KSPAN];
  int id = blockIdx.x;
  if (id < G5_BLOCKS) {
    gemm5_body<1, 1, 0>(sx, id % 9, id / 9, H23, b23, nullptr,
                        W24, W25, RM, RC, 4096, 4097);
  } else {
    id -= G5_BLOCKS;
    gemm5_body<1, 1, 1>(sx, id & 7, id >> 3, H3, b3, nullptr,
                        W31, W32, XM, XC, 4096, 4096);
  }
}

// ---------------- ARD (xi inline) + last-block GP solve ----------------
__global__ __launch_bounds__(256) void k_ardgp(
    const float* __restrict__ s,       const float* __restrict__ qxi_raw,
    const float* __restrict__ lqc_raw, const float* __restrict__ b11,
    const float* __restrict__ b12,     const float* __restrict__ eps_xi,
    const float* __restrict__ w,       const float* __restrict__ sigma,
    const float* __restrict__ t_in,    const float* __restrict__ eps_f,
    float* __restrict__ Kss, float* __restrict__ Kxs, int* __restrict__ cnt,
    float* __restrict__ fv, float* __restrict__ qfm, float* __restrict__ qfc)
{
  const int bid = blockIdx.x;
  const bool xs = (bid >= 25);
  int q = xs ? bid - 25 : bid;
  const int i = q / 5, j = q % 5;
  const float* bb = s + (long)j * DT;

  float sum = 0.f;
  for (int t = threadIdx.x; t < DT; t += 256) {
    float av;
    if (!xs) av = s[(long)i * DT + t];
    else {
      float qm = qxi_raw[(long)i * DT + t] + b11[t];
      float lq = lqc_raw[(long)i * DT + t] + b12[t];
      av = expf(0.5f * lq) * eps_xi[(long)i * DT + t] + qm;
    }
    float d = av - bb[t];
    sum += w[t] * d * d;
  }
  sum = wave_sum(sum);
  __shared__ float red[4];
  int lane = threadIdx.x & 63, wv = threadIdx.x >> 6;
  if (lane == 0) red[wv] = sum;
  __syncthreads();

  if (threadIdx.x == 0) {
    float tot = red[0] + red[1] + red[2] + red[3];
    float sg = sigma[0];
    float K = sg * sg * expf(-0.5f * tot);
    (xs ? Kxs : Kss)[i * 5 + j] = K;
    __threadfence();
    int old = atomicAdd(cnt, 1);
    if (old == 49) {
      __threadfence();
      double M[5][5], Inv[5][5];
      for (int a = 0; a < 5; ++a)
        for (int b = 0; b < 5; ++b) { M[a][b] = Kss[a * 5 + b]; Inv[a][b] = (a == b) ? 1.0 : 0.0; }
      for (int c = 0; c < 5; ++c) {
        int p = c; double best = fabs(M[c][c]);
        for (int r = c + 1; r < 5; ++r) if (fabs(M[r][c]) > best) { best = fabs(M[r][c]); p = r; }
        if (p != c)
          for (int k = 0; k < 5; ++k) {
            double tm = M[c][k]; M[c][k] = M[p][k]; M[p][k] = tm;
            tm = Inv[c][k]; Inv[c][k] = Inv[p][k]; Inv[p][k] = tm;
          }
        double piv = 1.0 / M[c][c];
        for (int k = 0; k < 5; ++k) { M[c][k] *= piv; Inv[c][k] *= piv; }
        for (int r = 0; r < 5; ++r) if (r != c) {
          double m = M[r][c];
          for (int k = 0; k < 5; ++k) { M[r][k] -= m * M[c][k]; Inv[r][k] -= m * Inv[c][k]; }
        }
      }
      double kk[5][5];
      for (int a = 0; a < 5; ++a)
        for (int b = 0; b < 5; ++b) {
          double acc = 0.0;
          for (int k = 0; k < 5; ++k) acc += (double)Kxs[a * 5 + k] * Inv[k][b];
          kk[a][b] = acc;
        }
      double sg2 = (double)sg * (double)sg;
      for (int a = 0; a < 5; ++a) {
        double qm = 0.0, qc = sg2;
        for (int b = 0; b < 5; ++b) { qm += kk[a][b] * (double)t_in[b]; qc -= kk[a][b] * (double)Kxs[a * 5 + b]; }
        if (qc < 1e-12) qc = 1e-12;
        qfm[a] = (float)qm;
        qfc[a] = (float)qc;
        fv[a]  = sqrtf((float)qc) * eps_f[a] + (float)qm;
      }
    }
  }
}

// ---------------- z sample + z outputs + kld1 ----------------
__global__ __launch_bounds__(256) void k_z(
    const float* __restrict__ zmraw, const float* __restrict__ zcraw,
    const float* __restrict__ b21,   const float* __restrict__ b22,
    const float* __restrict__ eps_z,
    float* __restrict__ out_zm, float* __restrict__ out_zc,
    float* __restrict__ zv, float* __restrict__ kld1sum)
{
  int idx = blockIdx.x * 256 + threadIdx.x;
  float term = 0.f;
  if (idx < B5 * DT) {
    int col = idx & (DT - 1);
    float zm = zmraw[idx] + b21[col];
    float zc = zcraw[idx] + b22[col];
    out_zm[idx] = zm; out_zc[idx] = zc;
    zv[idx] = expf(0.5f * zc) * eps_z[idx] + zm;
    term = -zc - 1.f + expf(zc) + zm * zm;
  }
  term = wave_sum(term);
  if ((threadIdx.x & 63) == 0) atomicAdd(kld1sum, term);
}

// ---------------- FIN: kld2 + x outputs + nll + scalar finalize ----------------
__global__ __launch_bounds__(256) void k_fin(
    const float* __restrict__ rm_raw, const float* __restrict__ rc_raw,
    const float* __restrict__ b24,    const float* __restrict__ b25,
    const float* __restrict__ qxi_raw,const float* __restrict__ lqc_raw,
    const float* __restrict__ b11,    const float* __restrict__ b12,
    const float* __restrict__ qfm,    const float* __restrict__ qfc,
    const float* __restrict__ xm_raw, const float* __restrict__ xc_raw,
    const float* __restrict__ b31,    const float* __restrict__ b32,
    const float* __restrict__ x,
    float* __restrict__ out_xm, float* __restrict__ out_xc,
    float* __restrict__ sums, int* __restrict__ cnt, float* __restrict__ out01)
{
  const int gtid = blockIdx.x * 256 + threadIdx.x;
  float t2 = 0.f, t3 = 0.f;
  if (gtid < B5 * DR) {
    int b = gtid / DR, col = gtid % DR;
    float rm = rm_raw[gtid] + b24[col];
    float rc = rc_raw[gtid] + b25[col];
    float qm, qc;
    if (col < DT) { qm = qxi_raw[(long)b * DT + col] + b11[col]; qc = lqc_raw[(long)b * DT + col] + b12[col]; }
    else          { qm = qfm[b]; qc = logf(qfc[b]); }
    float d = qm - rm;
    t2 = rc - qc - 1.f + expf(qc - rc) + d * d * expf(-rc);
  } else {
    int idx = gtid - B5 * DR;
    if (idx < B5 * DX) {
      int col = idx & (DX - 1);
      float xm = xm_raw[idx] + b31[col];
      float xc = xc_raw[idx] + b32[col];
      out_xm[idx] = xm; out_xc[idx] = xc;
      float d = x[idx] - xm;
      t3 = 1.14472988584940017f + xc + expf(-xc) * d * d;  // ln(pi) + ...
    }
  }
  t2 = wave_sum(t2);
  t3 = wave_sum(t3);
  if ((threadIdx.x & 63) == 0) {
    if (t2 != 0.f) atomicAdd(&sums[1], t2);
    if (t3 != 0.f) atomicAdd(&sums[2], t3);
  }
  __syncthreads();
  if (threadIdx.x == 0) {
    __threadfence();
    int old = atomicAdd(cnt, 1);
    if (old == (int)gridDim.x - 1) {
      __threadfence();
      out01[0] = 0.5f * (sums[0] + sums[1]) / (float)B5;
      out01[1] = 0.5f * sums[2] / (float)B5;
    }
  }
}

// ---------------- launch ----------------
extern "C" void kernel_launch(void* const* d_in, const int* in_sizes, int n_in,
                              void* d_out, int out_size, void* d_ws, size_t ws_size,
                              hipStream_t stream)
{
  const float* x      = (const float*)d_in[0];
  const float* eps_xi = (const float*)d_in[1];
  const float* eps_f  = (const float*)d_in[2];
  const float* eps_z  = (const float*)d_in[3];
  const float* W1  = (const float*)d_in[4];  const float* b1  = (const float*)d_in[5];
  const float* W11 = (const float*)d_in[6];  const float* b11 = (const float*)d_in[7];
  const float* W12 = (const float*)d_in[8];  const float* b12 = (const float*)d_in[9];
  const float* W2  = (const float*)d_in[10]; const float* b2  = (const float*)d_in[11];
  const float* W21 = (const float*)d_in[12]; const float* b21 = (const float*)d_in[13];
  const float* W22 = (const float*)d_in[14]; const float* b22 = (const float*)d_in[15];
  const float* W23 = (const float*)d_in[16]; const float* b23 = (const float*)d_in[17];
  const float* W24 = (const float*)d_in[18]; const float* b24 = (const float*)d_in[19];
  const float* W25 = (const float*)d_in[20]; const float* b25 = (const float*)d_in[21];
  const float* W3  = (const float*)d_in[22]; const float* b3  = (const float*)d_in[23];
  const float* W31 = (const float*)d_in[24]; const float* b31 = (const float*)d_in[25];
  const float* W32 = (const float*)d_in[26]; const float* b32 = (const float*)d_in[27];
  const float* s     = (const float*)d_in[28];
  const float* t     = (const float*)d_in[29];
  const float* sigma = (const float*)d_in[30];
  const float* w     = (const float*)d_in[31];

  float* ws  = (float*)d_ws;
  float* out = (float*)d_out;

  dim3 blk(256);

  // zero accumulators + loss sums + counters
  k_zero<<<(WS_ACCUM_END / 4 + 255) / 256, blk, 0, stream>>>(ws, WS_ACCUM_END);

  // G1: h1_raw = x @ W1                         (1024 blocks, 4/CU)
  gemm5<0,0,1><<<dim3(8,128), blk, 0, stream>>>(
      x, nullptr, nullptr, W1, nullptr, ws + WS_H1, nullptr, 4096, 4096);
  // G2: [qxi_raw, lqc_raw] = relu(h1_raw+b1) @ [W11, W12]
  gemm5<1,1,1><<<dim3(8,128), blk, 0, stream>>>(
      ws + WS_H1, b1, nullptr, W11, W12, ws + WS_QXI, ws + WS_LQC, 4096, 4096);
  // ARD (xi inline) + GP solve (last block)
  k_ardgp<<<50, blk, 0, stream>>>(
      s, ws + WS_QXI, ws + WS_LQC, b11, b12, eps_xi, w, sigma, t, eps_f,
      ws + WS_KSS, ws + WS_KXS, (int*)(ws + WS_CNT1),
      ws + WS_F, ws + WS_QFM, ws + WS_QFC);
  // G3: [zm_raw, zc_raw] = relu(f*W2+b2) @ [W21, W22]
  gemm5<2,1,1><<<dim3(8,128), blk, 0, stream>>>(
      ws + WS_F, W2, b2, W21, W22, ws + WS_ZM, ws + WS_ZC, 4096, 4096);
  // z sample + z outputs + kld1
  k_z<<<80, blk, 0, stream>>>(
      ws + WS_ZM, ws + WS_ZC, b21, b22, eps_z,
      out + 2, out + 2 + 20480, ws + WS_Z, ws + WS_SUMS);
  // G4+G6 merged: h23_raw = concat(x,z)@W23 ; h3_raw = z@W3   (3072 blocks)
  gemm5_G46<<<G4_BLOCKS + 8 * 128, blk, 0, stream>>>(
      x, ws + WS_Z, W23, ws + WS_H23, W3, ws + WS_H3);
  // G5+G7 merged: [rm,rc] = relu(h23+b23)@[W24,W25] ; [xm,xc] = relu(h3+b3)@[W31,W32]
  gemm5_G57<<<G5_BLOCKS + 8 * 128, blk, 0, stream>>>(
      ws + WS_H23, b23, W24, W25, ws + WS_RM, ws + WS_RC,
      ws + WS_H3,  b3,  W31, W32, ws + WS_XM, ws + WS_XC);
  // FIN: kld2 + x outputs + nll + scalar finalize
  k_fin<<<161, blk, 0, stream>>>(
      ws + WS_RM, ws + WS_RC, b24, b25,
      ws + WS_QXI, ws + WS_LQC, b11, b12,
      ws + WS_QFM, ws + WS_QFC,
      ws + WS_XM, ws + WS_XC, b31, b32, x,
      out + 2 + 40960, out + 2 + 61440,
      ws + WS_SUMS, (int*)(ws + WS_CNT2), out);
}

// Round 6
// 275.316 us; speedup vs baseline: 1.3443x; 1.3443x over previous
//
#include <hip/hip_runtime.h>
#include <math.h>

#define B5 5
#define DX 4096
#define DT 4096
#define DR 4097   // T + D

// ---------------- workspace layout (floats) ----------------
enum {
  WS_SUMS  = 0,                    // [kld1, kld2, nll]
  WS_CNT1  = 3,                    // ard completion counter (int)
  WS_CNT2  = 4,                    // fin completion counter (int)
  WS_ZERO_END = 8,                 // only these 8 floats are zeroed per call
  WS_QXI_F = 16,                   // finalized qxi_mean  (20480)
  WS_LQC_F = WS_QXI_F + 20480,     // finalized log_qxi_cov
  WS_XIV   = WS_LQC_F + 20480,     // xi sample
  WS_Z     = WS_XIV   + 20480,     // z sample
  WS_KSS   = WS_Z     + 20480,     // 25 (padded 32)
  WS_KXS   = WS_KSS + 32,
  WS_F     = WS_KXS + 32,          // 5 (padded 8)
  WS_QFM   = WS_F   + 8,
  WS_QFC   = WS_QFM + 8,
  WS_PART  = 82032,                // partial buffers, 16-aligned
  // partials: layout [ks][b][dout] ; always fully written before read
  WS_P_H1  = WS_PART,                       // 64*5*4096
  WS_P_QXI = WS_P_H1  + 1310720,
  WS_P_LQC = WS_P_QXI + 1310720,
  WS_P_ZM  = WS_P_LQC + 1310720,
  WS_P_ZC  = WS_P_ZM  + 1310720,
  WS_P_H23 = WS_P_ZC  + 1310720,            // 128*5*4096
  WS_P_H3  = WS_P_H23 + 2621440,            // 64*5*4096
  WS_P_RM  = WS_P_H3  + 1310720,            // 64*5*4097
  WS_P_RC  = WS_P_RM  + 1311040,
  WS_P_XM  = WS_P_RC  + 1311040,            // 64*5*4096
  WS_P_XC  = WS_P_XM  + 1310720,
  WS_END   = WS_P_XC  + 1310720             // ~63 MB
};

#define GROWS  64
#define GBLOCK 256

__device__ inline float wave_sum(float v) {
  #pragma unroll
  for (int o = 32; o > 0; o >>= 1) v += __shfl_down(v, o, 64);
  return v;
}

// ---------------- zero the 8 control floats ----------------
__global__ void k_zero(float* __restrict__ ws)
{
  if (threadIdx.x < WS_ZERO_END) ws[threadIdx.x] = 0.f;
}

// ---------------- GEMM body: P[ks] = prolog(.)[5,GROWS] @ W-rows ----------------
// R4-proven streaming loop. Output: per-split partial tile, plain stores (NO atomics).
// PROLOG: 0 raw p0 ; 2 relu(p0[b]*p1[k]+p2[k]) ; 3 concat(x,z) ;
//         4 relu(sum_ks partials(p0) + p1[k])   (fused reduction of producer partials)
template<int PROLOG, int DUAL, int ALIGNED, int NS>
__device__ __forceinline__ void gemm5_body(
    float sx[B5][GROWS], int bx, int by,
    const float* __restrict__ p0, const float* __restrict__ p1,
    const float* __restrict__ p2,
    const float* __restrict__ Wa, const float* __restrict__ Wb,
    float* __restrict__ Pa,       float* __restrict__ Pb,
    int din, int dout)
{
  const int tid = threadIdx.x;
  const long i0 = (long)by * GROWS;

  for (int t = tid; t < B5 * GROWS; t += GBLOCK) {
    int b  = t / GROWS;
    int il = t % GROWS;
    int i  = (int)i0 + il;
    float v;
    if (PROLOG == 0)      v = p0[(long)b * din + i];
    else if (PROLOG == 2) v = fmaxf(p0[b] * p1[i] + p2[i], 0.f);
    else if (PROLOG == 3) v = (i < DX) ? p0[(long)b * DX + i] : p1[(long)b * DT + (i - DX)];
    else {  // 4: reduce producer partials + bias + relu
      const float* pp = p0 + (long)b * din + i;
      float acc = 0.f;
      #pragma unroll 8
      for (int ks = 0; ks < NS; ++ks) acc += pp[(long)ks * (B5 * din)];
      v = fmaxf(acc + p1[i], 0.f);
    }
    sx[b][il] = v;
  }
  __syncthreads();

  long o0 = ((long)bx * GBLOCK + tid) * 2;
  if (o0 >= dout) return;
  const bool has2 = (o0 + 1 < dout);

  float accA[B5][2] = {};
  float accB[B5][2] = {};

  const float* wa = Wa + i0 * dout + o0;
  const float* wb = DUAL ? (Wb + i0 * dout + o0) : nullptr;

  #pragma unroll 4
  for (int il = 0; il < GROWS; ++il) {
    float w0a, w1a, w0b = 0.f, w1b = 0.f;
    if (ALIGNED) {
      float2 ta = *(const float2*)wa; w0a = ta.x; w1a = ta.y;
      if (DUAL) { float2 tb = *(const float2*)wb; w0b = tb.x; w1b = tb.y; }
    } else {
      w0a = wa[0]; w1a = has2 ? wa[1] : 0.f;
      if (DUAL) { w0b = wb[0]; w1b = has2 ? wb[1] : 0.f; }
    }
    #pragma unroll
    for (int b = 0; b < B5; ++b) {
      float xv = sx[b][il];
      accA[b][0] += xv * w0a; accA[b][1] += xv * w1a;
      if (DUAL) { accB[b][0] += xv * w0b; accB[b][1] += xv * w1b; }
    }
    wa += dout; if (DUAL) wb += dout;
  }

  // write per-split partials (plain stores; no device-scope atomics)
  #pragma unroll
  for (int b = 0; b < B5; ++b) {
    float* pa = Pa + ((long)by * B5 + b) * dout + o0;
    if (ALIGNED) *(float2*)pa = make_float2(accA[b][0], accA[b][1]);
    else { pa[0] = accA[b][0]; if (has2) pa[1] = accA[b][1]; }
    if (DUAL) {
      float* pb = Pb + ((long)by * B5 + b) * dout + o0;
      if (ALIGNED) *(float2*)pb = make_float2(accB[b][0], accB[b][1]);
      else { pb[0] = accB[b][0]; if (has2) pb[1] = accB[b][1]; }
    }
  }
}

template<int PROLOG, int DUAL, int ALIGNED, int NS>
__global__ __launch_bounds__(GBLOCK) void gemm5(
    const float* __restrict__ p0, const float* __restrict__ p1,
    const float* __restrict__ p2,
    const float* __restrict__ Wa, const float* __restrict__ Wb,
    float* __restrict__ Pa,       float* __restrict__ Pb,
    int din, int dout)
{
  __shared__ float sx[B5][GROWS];
  gemm5_body<PROLOG, DUAL, ALIGNED, NS>(sx, blockIdx.x, blockIdx.y,
      p0, p1, p2, Wa, Wb, Pa, Pb, din, dout);
}

// ---------------- k_xi: reduce qxi/lqc partials, finalize, sample xi ----------------
__global__ __launch_bounds__(256) void k_xi(
    const float* __restrict__ Pq, const float* __restrict__ Pl,
    const float* __restrict__ b11, const float* __restrict__ b12,
    const float* __restrict__ eps_xi,
    float* __restrict__ qf, float* __restrict__ lf, float* __restrict__ xiv)
{
  int idx = blockIdx.x * 256 + threadIdx.x;
  if (idx >= B5 * DT) return;
  int b = idx >> 12, col = idx & (DT - 1);
  const float* pq = Pq + (long)b * DT + col;
  const float* pl = Pl + (long)b * DT + col;
  float sq = 0.f, sl = 0.f;
  #pragma unroll 8
  for (int ks = 0; ks < 64; ++ks) { sq += pq[(long)ks * (B5 * DT)]; sl += pl[(long)ks * (B5 * DT)]; }
  float qm = sq + b11[col];
  float lq = sl + b12[col];
  qf[idx] = qm; lf[idx] = lq;
  xiv[idx] = expf(0.5f * lq) * eps_xi[idx] + qm;
}

// ---------------- ARD + last-block GP solve ----------------
__global__ __launch_bounds__(256) void k_ardgp(
    const float* __restrict__ s,    const float* __restrict__ xiv,
    const float* __restrict__ w,    const float* __restrict__ sigma,
    const float* __restrict__ t_in, const float* __restrict__ eps_f,
    float* __restrict__ Kss, float* __restrict__ Kxs, int* __restrict__ cnt,
    float* __restrict__ fv, float* __restrict__ qfm, float* __restrict__ qfc)
{
  const int bid = blockIdx.x;
  const bool xs = (bid >= 25);
  int q = xs ? bid - 25 : bid;
  const int i = q / 5, j = q % 5;
  const float* aa = xs ? (xiv + (long)i * DT) : (s + (long)i * DT);
  const float* bb = s + (long)j * DT;

  float sum = 0.f;
  for (int t = threadIdx.x; t < DT; t += 256) {
    float d = aa[t] - bb[t];
    sum += w[t] * d * d;
  }
  sum = wave_sum(sum);
  __shared__ float red[4];
  int lane = threadIdx.x & 63, wv = threadIdx.x >> 6;
  if (lane == 0) red[wv] = sum;
  __syncthreads();

  if (threadIdx.x == 0) {
    float tot = red[0] + red[1] + red[2] + red[3];
    float sg = sigma[0];
    float K = sg * sg * expf(-0.5f * tot);
    (xs ? Kxs : Kss)[i * 5 + j] = K;
    __threadfence();
    int old = atomicAdd(cnt, 1);
    if (old == 49) {
      __threadfence();
      double M[5][5], Inv[5][5];
      for (int a = 0; a < 5; ++a)
        for (int b = 0; b < 5; ++b) { M[a][b] = Kss[a * 5 + b]; Inv[a][b] = (a == b) ? 1.0 : 0.0; }
      for (int c = 0; c < 5; ++c) {
        int p = c; double best = fabs(M[c][c]);
        for (int r = c + 1; r < 5; ++r) if (fabs(M[r][c]) > best) { best = fabs(M[r][c]); p = r; }
        if (p != c)
          for (int k = 0; k < 5; ++k) {
            double tm = M[c][k]; M[c][k] = M[p][k]; M[p][k] = tm;
            tm = Inv[c][k]; Inv[c][k] = Inv[p][k]; Inv[p][k] = tm;
          }
        double piv = 1.0 / M[c][c];
        for (int k = 0; k < 5; ++k) { M[c][k] *= piv; Inv[c][k] *= piv; }
        for (int r = 0; r < 5; ++r) if (r != c) {
          double m = M[r][c];
          for (int k = 0; k < 5; ++k) { M[r][k] -= m * M[c][k]; Inv[r][k] -= m * Inv[c][k]; }
        }
      }
      double kk[5][5];
      for (int a = 0; a < 5; ++a)
        for (int b = 0; b < 5; ++b) {
          double acc = 0.0;
          for (int k = 0; k < 5; ++k) acc += (double)Kxs[a * 5 + k] * Inv[k][b];
          kk[a][b] = acc;
        }
      double sg2 = (double)sg * (double)sg;
      for (int a = 0; a < 5; ++a) {
        double qm = 0.0, qc = sg2;
        for (int b = 0; b < 5; ++b) { qm += kk[a][b] * (double)t_in[b]; qc -= kk[a][b] * (double)Kxs[a * 5 + b]; }
        if (qc < 1e-12) qc = 1e-12;
        qfm[a] = (float)qm;
        qfc[a] = (float)qc;
        fv[a]  = sqrtf((float)qc) * eps_f[a] + (float)qm;
      }
    }
  }
}

// ---------------- k_z: reduce zm/zc partials, outputs, sample z, kld1 ----------------
__global__ __launch_bounds__(256) void k_z(
    const float* __restrict__ Pm, const float* __restrict__ Pc,
    const float* __restrict__ b21, const float* __restrict__ b22,
    const float* __restrict__ eps_z,
    float* __restrict__ out_zm, float* __restrict__ out_zc,
    float* __restrict__ zv, float* __restrict__ kld1sum)
{
  int idx = blockIdx.x * 256 + threadIdx.x;
  float term = 0.f;
  if (idx < B5 * DT) {
    int b = idx >> 12, col = idx & (DT - 1);
    const float* pm = Pm + (long)b * DT + col;
    const float* pc = Pc + (long)b * DT + col;
    float sm = 0.f, sc = 0.f;
    #pragma unroll 8
    for (int ks = 0; ks < 64; ++ks) { sm += pm[(long)ks * (B5 * DT)]; sc += pc[(long)ks * (B5 * DT)]; }
    float zm = sm + b21[col];
    float zc = sc + b22[col];
    out_zm[idx] = zm; out_zc[idx] = zc;
    zv[idx] = expf(0.5f * zc) * eps_z[idx] + zm;
    term = -zc - 1.f + expf(zc) + zm * zm;
  }
  term = wave_sum(term);
  if ((threadIdx.x & 63) == 0) atomicAdd(kld1sum, term);
}

// ---------------- FIN: reduce rm/rc/xm/xc partials + kld2 + nll + outputs ----------------
__global__ __launch_bounds__(256) void k_fin(
    const float* __restrict__ Prm, const float* __restrict__ Prc,
    const float* __restrict__ b24, const float* __restrict__ b25,
    const float* __restrict__ qxi, const float* __restrict__ lqc,
    const float* __restrict__ qfm, const float* __restrict__ qfc,
    const float* __restrict__ Pxm, const float* __restrict__ Pxc,
    const float* __restrict__ b31, const float* __restrict__ b32,
    const float* __restrict__ x,
    float* __restrict__ out_xm, float* __restrict__ out_xc,
    float* __restrict__ sums, int* __restrict__ cnt, float* __restrict__ out01)
{
  const int gtid = blockIdx.x * 256 + threadIdx.x;
  float t2 = 0.f, t3 = 0.f;
  if (gtid < B5 * DR) {
    int b = gtid / DR, col = gtid % DR;
    const float* pm = Prm + (long)b * DR + col;
    const float* pc = Prc + (long)b * DR + col;
    float sm = 0.f, sc = 0.f;
    #pragma unroll 8
    for (int ks = 0; ks < 64; ++ks) { sm += pm[(long)ks * (B5 * DR)]; sc += pc[(long)ks * (B5 * DR)]; }
    float rm = sm + b24[col];
    float rc = sc + b25[col];
    float qm, qc;
    if (col < DT) { qm = qxi[(long)b * DT + col]; qc = lqc[(long)b * DT + col]; }
    else          { qm = qfm[b]; qc = logf(qfc[b]); }
    float d = qm - rm;
    t2 = rc - qc - 1.f + expf(qc - rc) + d * d * expf(-rc);
  } else {
    int idx = gtid - B5 * DR;
    if (idx < B5 * DX) {
      int b = idx >> 12, col = idx & (DX - 1);
      const float* pm = Pxm + (long)b * DX + col;
      const float* pc = Pxc + (long)b * DX + col;
      float sm = 0.f, sc = 0.f;
      #pragma unroll 8
      for (int ks = 0; ks < 64; ++ks) { sm += pm[(long)ks * (B5 * DX)]; sc += pc[(long)ks * (B5 * DX)]; }
      float xm = sm + b31[col];
      float xc = sc + b32[col];
      out_xm[idx] = xm; out_xc[idx] = xc;
      float d = x[idx] - xm;
      t3 = 1.14472988584940017f + xc + expf(-xc) * d * d;  // ln(pi) + ...
    }
  }
  t2 = wave_sum(t2);
  t3 = wave_sum(t3);
  if ((threadIdx.x & 63) == 0) {
    if (t2 != 0.f) atomicAdd(&sums[1], t2);
    if (t3 != 0.f) atomicAdd(&sums[2], t3);
  }
  __syncthreads();
  if (threadIdx.x == 0) {
    __threadfence();
    int old = atomicAdd(cnt, 1);
    if (old == (int)gridDim.x - 1) {
      __threadfence();
      out01[0] = 0.5f * (sums[0] + sums[1]) / (float)B5;
      out01[1] = 0.5f * sums[2] / (float)B5;
    }
  }
}

// ---------------- launch ----------------
extern "C" void kernel_launch(void* const* d_in, const int* in_sizes, int n_in,
                              void* d_out, int out_size, void* d_ws, size_t ws_size,
                              hipStream_t stream)
{
  const float* x      = (const float*)d_in[0];
  const float* eps_xi = (const float*)d_in[1];
  const float* eps_f  = (const float*)d_in[2];
  const float* eps_z  = (const float*)d_in[3];
  const float* W1  = (const float*)d_in[4];  const float* b1  = (const float*)d_in[5];
  const float* W11 = (const float*)d_in[6];  const float* b11 = (const float*)d_in[7];
  const float* W12 = (const float*)d_in[8];  const float* b12 = (const float*)d_in[9];
  const float* W2  = (const float*)d_in[10]; const float* b2  = (const float*)d_in[11];
  const float* W21 = (const float*)d_in[12]; const float* b21 = (const float*)d_in[13];
  const float* W22 = (const float*)d_in[14]; const float* b22 = (const float*)d_in[15];
  const float* W23 = (const float*)d_in[16]; const float* b23 = (const float*)d_in[17];
  const float* W24 = (const float*)d_in[18]; const float* b24 = (const float*)d_in[19];
  const float* W25 = (const float*)d_in[20]; const float* b25 = (const float*)d_in[21];
  const float* W3  = (const float*)d_in[22]; const float* b3  = (const float*)d_in[23];
  const float* W31 = (const float*)d_in[24]; const float* b31 = (const float*)d_in[25];
  const float* W32 = (const float*)d_in[26]; const float* b32 = (const float*)d_in[27];
  const float* s     = (const float*)d_in[28];
  const float* t     = (const float*)d_in[29];
  const float* sigma = (const float*)d_in[30];
  const float* w     = (const float*)d_in[31];

  float* ws  = (float*)d_ws;
  float* out = (float*)d_out;

  dim3 blk(256);

  // zero loss sums + counters only (partials are always fully overwritten)
  k_zero<<<1, 64, 0, stream>>>(ws);

  // G1: h1 partials = x @ W1
  gemm5<0,0,1,1><<<dim3(8,64), blk, 0, stream>>>(
      x, nullptr, nullptr, W1, nullptr, ws + WS_P_H1, nullptr, 4096, 4096);
  // G2: qxi/lqc partials = relu(sum(P_H1)+b1) @ [W11, W12]
  gemm5<4,1,1,64><<<dim3(8,64), blk, 0, stream>>>(
      ws + WS_P_H1, b1, nullptr, W11, W12, ws + WS_P_QXI, ws + WS_P_LQC, 4096, 4096);
  // k_xi: finalize qxi/lqc + sample xi
  k_xi<<<80, blk, 0, stream>>>(
      ws + WS_P_QXI, ws + WS_P_LQC, b11, b12, eps_xi,
      ws + WS_QXI_F, ws + WS_LQC_F, ws + WS_XIV);
  // ARD + GP solve
  k_ardgp<<<50, blk, 0, stream>>>(
      s, ws + WS_XIV, w, sigma, t, eps_f,
      ws + WS_KSS, ws + WS_KXS, (int*)(ws + WS_CNT1),
      ws + WS_F, ws + WS_QFM, ws + WS_QFC);
  // G3: zm/zc partials = relu(f*W2+b2) @ [W21, W22]
  gemm5<2,1,1,1><<<dim3(8,64), blk, 0, stream>>>(
      ws + WS_F, W2, b2, W21, W22, ws + WS_P_ZM, ws + WS_P_ZC, 4096, 4096);
  // k_z: finalize zm/zc + sample z + kld1
  k_z<<<80, blk, 0, stream>>>(
      ws + WS_P_ZM, ws + WS_P_ZC, b21, b22, eps_z,
      out + 2, out + 2 + 20480, ws + WS_Z, ws + WS_SUMS);
  // G4: h23 partials = concat(x,z) @ W23
  gemm5<3,0,1,1><<<dim3(8,128), blk, 0, stream>>>(
      x, ws + WS_Z, nullptr, W23, nullptr, ws + WS_P_H23, nullptr, 8192, 4096);
  // G5: rm/rc partials = relu(sum(P_H23)+b23) @ [W24, W25]  (dout=4097)
  gemm5<4,1,0,128><<<dim3(9,64), blk, 0, stream>>>(
      ws + WS_P_H23, b23, nullptr, W24, W25, ws + WS_P_RM, ws + WS_P_RC, 4096, 4097);
  // G6: h3 partials = z @ W3
  gemm5<0,0,1,1><<<dim3(8,64), blk, 0, stream>>>(
      ws + WS_Z, nullptr, nullptr, W3, nullptr, ws + WS_P_H3, nullptr, 4096, 4096);
  // G7: xm/xc partials = relu(sum(P_H3)+b3) @ [W31, W32]
  gemm5<4,1,1,64><<<dim3(8,64), blk, 0, stream>>>(
      ws + WS_P_H3, b3, nullptr, W31, W32, ws + WS_P_XM, ws + WS_P_XC, 4096, 4096);
  // FIN: reduce + kld2 + nll + x outputs + scalar finalize
  k_fin<<<161, blk, 0, stream>>>(
      ws + WS_P_RM, ws + WS_P_RC, b24, b25,
      ws + WS_QXI_F, ws + WS_LQC_F,
      ws + WS_QFM, ws + WS_QFC,
      ws + WS_P_XM, ws + WS_P_XC, b31, b32, x,
      out + 2 + 40960, out + 2 + 61440,
      ws + WS_SUMS, (int*)(ws + WS_CNT2), out);
}